// Round 7
// baseline (262.245 us; speedup 1.0000x reference)
//
#include <hip/hip_runtime.h>

// Fused, 4 atoms/thread. Gathers use ONE dwordx3 (float3) load each instead
// of 3 dword loads -- 3x fewer VMEM instructions per wave so 3x more random
// lines in flight at equal vmcnt queue depth. z/x gathered unconditionally
// (R6 predication of z/x regressed: FETCH -10MB only, time +11us), y
// predicated (t==2|3). Rotation carries only x,z rows; y = cross(z,x).
// MEASURED REJECTS: non-temporal ld/st (2x regression, partial-line RMW);
// two-pass ws split (gather misses unchanged + scratch round-trip);
// z/x gather predication (FETCH ~flat: L2-miss re-fetch of coords is
// capacity-driven, not request-count-driven).

__device__ __forceinline__ float3 nrm3(float ax, float ay, float az) {
    float s = ax * ax + ay * ay + az * az;
    float r = 1.0f / sqrtf(s);
    return make_float3(ax * r, ay * r, az * r);
}

// Rotation x row (R[0..2]) and z row (R[6..8]) from pre-gathered deltas.
__device__ __forceinline__ void rot_from_deltas(
    int t, const float* dz, const float* dx, const float* dy, float R[9])
{
    if (t == 5) {
        R[0] = 1.0f; R[1] = 0.0f; R[2] = 0.0f;
        R[6] = 0.0f; R[7] = 0.0f; R[8] = 1.0f;
        return;
    }

    float3 zv = nrm3(dz[0], dz[1], dz[2]);

    float3 xv;
    if (t == 4) {
        xv = make_float3(1.0f - zv.x, zv.x, 0.0f);
    } else {
        xv = nrm3(dx[0], dx[1], dx[2]);
    }

    if (t == 1) {
        zv = nrm3(zv.x + xv.x, zv.y + xv.y, zv.z + xv.z);
    }

    if (t == 2 || t == 3) {
        float3 yn = nrm3(dy[0], dy[1], dy[2]);
        if (t == 2) {
            xv = nrm3(xv.x + yn.x, xv.y + yn.y, xv.z + yn.z);
        } else {
            zv = nrm3(zv.x + xv.x + yn.x, zv.y + xv.y + yn.y, zv.z + xv.z + yn.z);
        }
    }

    float dzx = zv.x * xv.x + zv.y * xv.y + zv.z * xv.z;
    xv = nrm3(xv.x - zv.x * dzx, xv.y - zv.y * dzx, xv.z - zv.z * dzx);

    R[0] = xv.x; R[1] = xv.y; R[2] = xv.z;
    R[6] = zv.x; R[7] = zv.y; R[8] = zv.z;
}

// Full apply given x row + z row (y = cross(z,x)).
__device__ __forceinline__ void apply_rot_xz(
    const float xv[3], const float zv[3], const float dp[3], const float Q[9],
    float od[3], float oq[9])
{
    float R[9];
    R[0] = xv[0]; R[1] = xv[1]; R[2] = xv[2];
    R[3] = zv[1] * xv[2] - zv[2] * xv[1];
    R[4] = zv[2] * xv[0] - zv[0] * xv[2];
    R[5] = zv[0] * xv[1] - zv[1] * xv[0];
    R[6] = zv[0]; R[7] = zv[1]; R[8] = zv[2];

    od[0] = dp[0] * R[0] + dp[1] * R[3] + dp[2] * R[6];
    od[1] = dp[0] * R[1] + dp[1] * R[4] + dp[2] * R[7];
    od[2] = dp[0] * R[2] + dp[1] * R[5] + dp[2] * R[8];

    float M[9];
#pragma unroll
    for (int a = 0; a < 3; ++a)
#pragma unroll
        for (int l = 0; l < 3; ++l)
            M[a * 3 + l] = R[0 * 3 + a] * Q[0 * 3 + l]
                         + R[1 * 3 + a] * Q[1 * 3 + l]
                         + R[2 * 3 + a] * Q[2 * 3 + l];
#pragma unroll
    for (int a = 0; a < 3; ++a)
#pragma unroll
        for (int b = 0; b < 3; ++b)
            oq[a * 3 + b] = M[a * 3 + 0] * R[0 * 3 + b]
                          + M[a * 3 + 1] * R[1 * 3 + b]
                          + M[a * 3 + 2] * R[2 * 3 + b];
}

__global__ __launch_bounds__(256) void mp_rot4_x3_kernel(
    const float* __restrict__ coords,
    const int* __restrict__ za,
    const int* __restrict__ xa,
    const int* __restrict__ ya,
    const int* __restrict__ at,
    const float* __restrict__ dip,
    const float* __restrict__ quad,
    float* __restrict__ out_d,
    float* __restrict__ out_q,
    int ngroups, int n)
{
    int g = blockIdx.x * blockDim.x + threadIdx.x;
    if (g >= ngroups) return;
    int base = 4 * g;

    if (base + 4 <= n) {
        int4 z4 = ((const int4*)za)[g];
        int4 x4 = ((const int4*)xa)[g];
        int4 y4 = ((const int4*)ya)[g];
        int4 t4 = ((const int4*)at)[g];
        int zi[4] = {z4.x, z4.y, z4.z, z4.w};
        int xi[4] = {x4.x, x4.y, x4.z, x4.w};
        int yi[4] = {y4.x, y4.y, y4.z, y4.w};
        int ti[4] = {t4.x, t4.y, t4.z, t4.w};

        float4 cA = ((const float4*)coords)[3 * g + 0];
        float4 cB = ((const float4*)coords)[3 * g + 1];
        float4 cC = ((const float4*)coords)[3 * g + 2];
        float c[12] = {cA.x, cA.y, cA.z, cA.w, cB.x, cB.y, cB.z, cB.w,
                       cC.x, cC.y, cC.z, cC.w};

        // ---- hoisted gathers: ONE dwordx3 load per gather ----
        float3 gz[4], gx[4], gy[4];
#pragma unroll
        for (int a = 0; a < 4; ++a)
            gz[a] = *(const float3*)(coords + 3 * zi[a]);
#pragma unroll
        for (int a = 0; a < 4; ++a)
            gx[a] = *(const float3*)(coords + 3 * xi[a]);
#pragma unroll
        for (int a = 0; a < 4; ++a) {
            if ((ti[a] == 2) | (ti[a] == 3))
                gy[a] = *(const float3*)(coords + 3 * yi[a]);
            else
                gy[a] = make_float3(0.0f, 0.0f, 0.0f);
        }

        // sequential streams
        float4 dA = ((const float4*)dip)[3 * g + 0];
        float4 dB = ((const float4*)dip)[3 * g + 1];
        float4 dC = ((const float4*)dip)[3 * g + 2];
        float dp[12] = {dA.x, dA.y, dA.z, dA.w, dB.x, dB.y, dB.z, dB.w,
                        dC.x, dC.y, dC.z, dC.w};

        float q[36];
#pragma unroll
        for (int k = 0; k < 9; ++k) {
            float4 v = ((const float4*)quad)[9 * g + k];
            q[4 * k + 0] = v.x; q[4 * k + 1] = v.y;
            q[4 * k + 2] = v.z; q[4 * k + 3] = v.w;
        }

        float od[12], oq[36];
#pragma unroll
        for (int a = 0; a < 4; ++a) {
            float dz[3] = {gz[a].x - c[3 * a + 0], gz[a].y - c[3 * a + 1], gz[a].z - c[3 * a + 2]};
            float dx[3] = {gx[a].x - c[3 * a + 0], gx[a].y - c[3 * a + 1], gx[a].z - c[3 * a + 2]};
            float dy[3] = {gy[a].x - c[3 * a + 0], gy[a].y - c[3 * a + 1], gy[a].z - c[3 * a + 2]};
            float R[9];
            rot_from_deltas(ti[a], dz, dx, dy, R);
            apply_rot_xz(&R[0], &R[6], &dp[3 * a], &q[9 * a],
                         &od[3 * a], &oq[9 * a]);
        }

        ((float4*)out_d)[3 * g + 0] = make_float4(od[0], od[1], od[2], od[3]);
        ((float4*)out_d)[3 * g + 1] = make_float4(od[4], od[5], od[6], od[7]);
        ((float4*)out_d)[3 * g + 2] = make_float4(od[8], od[9], od[10], od[11]);
#pragma unroll
        for (int k = 0; k < 9; ++k)
            ((float4*)out_q)[9 * g + k] = make_float4(oq[4 * k + 0], oq[4 * k + 1],
                                                      oq[4 * k + 2], oq[4 * k + 3]);
    } else {
        // tail: scalar per-atom fallback
        for (int i = base; i < n; ++i) {
            int t = at[i];
            float cx = coords[3 * i + 0], cy = coords[3 * i + 1], cz = coords[3 * i + 2];
            int zi = za[i], xi = xa[i], yi = ya[i];
            float dz[3] = {coords[3 * zi + 0] - cx, coords[3 * zi + 1] - cy, coords[3 * zi + 2] - cz};
            float dx[3] = {coords[3 * xi + 0] - cx, coords[3 * xi + 1] - cy, coords[3 * xi + 2] - cz};
            float dy[3] = {0.0f, 0.0f, 0.0f};
            if (t == 2 || t == 3) {
                dy[0] = coords[3 * yi + 0] - cx; dy[1] = coords[3 * yi + 1] - cy; dy[2] = coords[3 * yi + 2] - cz;
            }
            float R[9];
            rot_from_deltas(t, dz, dx, dy, R);
            float dpl[3] = {dip[3 * i + 0], dip[3 * i + 1], dip[3 * i + 2]};
            float Q[9];
#pragma unroll
            for (int k = 0; k < 9; ++k) Q[k] = quad[9 * i + k];
            float od[3], oq[9];
            apply_rot_xz(&R[0], &R[6], dpl, Q, od, oq);
#pragma unroll
            for (int k = 0; k < 3; ++k) out_d[3 * i + k] = od[k];
#pragma unroll
            for (int k = 0; k < 9; ++k) out_q[9 * i + k] = oq[k];
        }
    }
}

extern "C" void kernel_launch(void* const* d_in, const int* in_sizes, int n_in,
                              void* d_out, int out_size, void* d_ws, size_t ws_size,
                              hipStream_t stream) {
    const float* coords = (const float*)d_in[0];
    const int* za = (const int*)d_in[1];
    const int* xa = (const int*)d_in[2];
    const int* ya = (const int*)d_in[3];
    const int* at = (const int*)d_in[4];
    const float* dip = (const float*)d_in[5];
    const float* quad = (const float*)d_in[6];

    int n = in_sizes[1];  // z_atoms count == N
    float* out_d = (float*)d_out;
    float* out_q = out_d + (size_t)3 * n;

    int ngroups = (n + 3) / 4;
    int block = 256;
    int grid = (ngroups + block - 1) / block;
    mp_rot4_x3_kernel<<<grid, block, 0, stream>>>(coords, za, xa, ya, at,
                                                  dip, quad, out_d, out_q,
                                                  ngroups, n);
}

// Round 8
// 240.916 us; speedup vs baseline: 1.0885x; 1.0885x over previous
//
#include <hip/hip_runtime.h>

// 1 atom/thread, minimal body (~45 VGPR) for max occupancy (8 waves/SIMD),
// with all gathers hoisted to the top so each wave keeps ~27 independent
// VMEM ops in flight. z/x gathers unconditional, y predicated (t==2|3).
// Rotation carries only x,z rows; y = cross(z,x) at apply time.
// MEASURED REJECTS: non-temporal ld/st (2x regression, partial-line RMW);
// two-pass ws split (pure streaming pass only ran 2.4 TB/s -> regime is
// latency-bound, not bytes-bound); z/x gather predication (occupancy drop,
// FETCH ~flat); float3 dwordx3 gathers (19% line-straddle, FETCH +135MB).

__device__ __forceinline__ float3 nrm3(float ax, float ay, float az) {
    float s = ax * ax + ay * ay + az * az;
    float r = 1.0f / sqrtf(s);
    return make_float3(ax * r, ay * r, az * r);
}

// Rotation x row (R[0..2]) and z row (R[6..8]) from pre-gathered deltas.
__device__ __forceinline__ void rot_from_deltas(
    int t, const float* dz, const float* dx, const float* dy, float R[9])
{
    if (t == 5) {
        R[0] = 1.0f; R[1] = 0.0f; R[2] = 0.0f;
        R[6] = 0.0f; R[7] = 0.0f; R[8] = 1.0f;
        return;
    }

    float3 zv = nrm3(dz[0], dz[1], dz[2]);

    float3 xv;
    if (t == 4) {
        xv = make_float3(1.0f - zv.x, zv.x, 0.0f);
    } else {
        xv = nrm3(dx[0], dx[1], dx[2]);
    }

    if (t == 1) {
        zv = nrm3(zv.x + xv.x, zv.y + xv.y, zv.z + xv.z);
    }

    if (t == 2 || t == 3) {
        float3 yn = nrm3(dy[0], dy[1], dy[2]);
        if (t == 2) {
            xv = nrm3(xv.x + yn.x, xv.y + yn.y, xv.z + yn.z);
        } else {
            zv = nrm3(zv.x + xv.x + yn.x, zv.y + xv.y + yn.y, zv.z + xv.z + yn.z);
        }
    }

    float dzx = zv.x * xv.x + zv.y * xv.y + zv.z * xv.z;
    xv = nrm3(xv.x - zv.x * dzx, xv.y - zv.y * dzx, xv.z - zv.z * dzx);

    R[0] = xv.x; R[1] = xv.y; R[2] = xv.z;
    R[6] = zv.x; R[7] = zv.y; R[8] = zv.z;
}

// Full apply given x row + z row (y = cross(z,x)).
__device__ __forceinline__ void apply_rot_xz(
    const float xv[3], const float zv[3], const float dp[3], const float Q[9],
    float od[3], float oq[9])
{
    float R[9];
    R[0] = xv[0]; R[1] = xv[1]; R[2] = xv[2];
    R[3] = zv[1] * xv[2] - zv[2] * xv[1];
    R[4] = zv[2] * xv[0] - zv[0] * xv[2];
    R[5] = zv[0] * xv[1] - zv[1] * xv[0];
    R[6] = zv[0]; R[7] = zv[1]; R[8] = zv[2];

    od[0] = dp[0] * R[0] + dp[1] * R[3] + dp[2] * R[6];
    od[1] = dp[0] * R[1] + dp[1] * R[4] + dp[2] * R[7];
    od[2] = dp[0] * R[2] + dp[1] * R[5] + dp[2] * R[8];

    float M[9];
#pragma unroll
    for (int a = 0; a < 3; ++a)
#pragma unroll
        for (int l = 0; l < 3; ++l)
            M[a * 3 + l] = R[0 * 3 + a] * Q[0 * 3 + l]
                         + R[1 * 3 + a] * Q[1 * 3 + l]
                         + R[2 * 3 + a] * Q[2 * 3 + l];
#pragma unroll
    for (int a = 0; a < 3; ++a)
#pragma unroll
        for (int b = 0; b < 3; ++b)
            oq[a * 3 + b] = M[a * 3 + 0] * R[0 * 3 + b]
                          + M[a * 3 + 1] * R[1 * 3 + b]
                          + M[a * 3 + 2] * R[2 * 3 + b];
}

__global__ __launch_bounds__(256, 8) void mp_rot1_hoist_kernel(
    const float* __restrict__ coords,
    const int* __restrict__ za,
    const int* __restrict__ xa,
    const int* __restrict__ ya,
    const int* __restrict__ at,
    const float* __restrict__ dip,
    const float* __restrict__ quad,
    float* __restrict__ out_d,
    float* __restrict__ out_q,
    int n)
{
    int i = blockIdx.x * blockDim.x + threadIdx.x;
    if (i >= n) return;

    // ---- issue ALL loads up front; math only after ----
    int t  = at[i];
    int zi = za[i];
    int xi = xa[i];
    int yi = ya[i];

    float cx = coords[3 * i + 0];
    float cy = coords[3 * i + 1];
    float cz = coords[3 * i + 2];

    // hoisted gathers: z, x unconditional; y predicated but issued here
    float gzx = coords[3 * zi + 0];
    float gzy = coords[3 * zi + 1];
    float gzz = coords[3 * zi + 2];
    float gxx = coords[3 * xi + 0];
    float gxy = coords[3 * xi + 1];
    float gxz = coords[3 * xi + 2];
    bool needy = (t == 2) | (t == 3);
    float gyx = 0.0f, gyy = 0.0f, gyz = 0.0f;
    if (needy) {
        gyx = coords[3 * yi + 0];
        gyy = coords[3 * yi + 1];
        gyz = coords[3 * yi + 2];
    }

    // sequential streams
    float dp[3] = {dip[3 * i + 0], dip[3 * i + 1], dip[3 * i + 2]};
    float Q[9];
#pragma unroll
    for (int k = 0; k < 9; ++k) Q[k] = quad[9 * i + k];

    // ---- math ----
    float dz[3] = {gzx - cx, gzy - cy, gzz - cz};
    float dx[3] = {gxx - cx, gxy - cy, gxz - cz};
    float dy[3] = {gyx - cx, gyy - cy, gyz - cz};

    float R[9];
    rot_from_deltas(t, dz, dx, dy, R);

    float od[3], oq[9];
    apply_rot_xz(&R[0], &R[6], dp, Q, od, oq);

    // ---- stores ----
#pragma unroll
    for (int k = 0; k < 3; ++k) out_d[3 * i + k] = od[k];
#pragma unroll
    for (int k = 0; k < 9; ++k) out_q[9 * i + k] = oq[k];
}

extern "C" void kernel_launch(void* const* d_in, const int* in_sizes, int n_in,
                              void* d_out, int out_size, void* d_ws, size_t ws_size,
                              hipStream_t stream) {
    const float* coords = (const float*)d_in[0];
    const int* za = (const int*)d_in[1];
    const int* xa = (const int*)d_in[2];
    const int* ya = (const int*)d_in[3];
    const int* at = (const int*)d_in[4];
    const float* dip = (const float*)d_in[5];
    const float* quad = (const float*)d_in[6];

    int n = in_sizes[1];  // z_atoms count == N
    float* out_d = (float*)d_out;
    float* out_q = out_d + (size_t)3 * n;

    int block = 256;
    int grid = (n + block - 1) / block;
    mp_rot1_hoist_kernel<<<grid, block, 0, stream>>>(coords, za, xa, ya, at,
                                                     dip, quad, out_d, out_q, n);
}

// Round 9
// 207.680 us; speedup vs baseline: 1.2627x; 1.1600x over previous
//
#include <hip/hip_runtime.h>

// FINAL: measured-best variant (Round-1 structure, 208 us).
// One thread per atom, branchy gathers = minimum random-line traffic
// (avg 1.83 gathers/atom: z for t!=5, x for t<=3, y for t in {2,3}).
// 20 VGPR, high occupancy.
//
// Composed model (8 rounds of probes): time ~= L2-fill bytes / ~4 TB/s.
//   304 MB sequential fetch + ~350 MB random gather line fills + 187 MB
//   writes ~= 840 MB -> ~210 us. All structural variants (vec4 4-atom,
//   two-pass split, predicated gathers, wide gathers, max-occupancy
//   hoisted) land 208-262 us; byte count through L2 is the invariant
//   predictor, and its floor is set by the random gather pattern.
// MEASURED REJECTS: non-temporal ld/st (2x regression: partial-line
// no-allocate stores RMW-amplify WRITE 193->514 MB); two-pass ws split
// (gather misses unchanged + 96 MB scratch round-trip); gather
// predication-with-hoist (FETCH ~flat, occupancy drop); float3 gathers
// (compiler emits dwordx4 -> 12.5% line-straddle, FETCH +135 MB);
// 1-atom full-hoist (x-gather 4/6->6/6 adds ~114 MB FETCH, +33 us).

__device__ __forceinline__ float3 nrm3(float ax, float ay, float az) {
    float s = ax * ax + ay * ay + az * az;
    float r = 1.0f / sqrtf(s);
    return make_float3(ax * r, ay * r, az * r);
}

__global__ __launch_bounds__(256) void mp_rot_kernel(
    const float* __restrict__ coords,
    const int* __restrict__ za,
    const int* __restrict__ xa,
    const int* __restrict__ ya,
    const int* __restrict__ at,
    const float* __restrict__ dip,
    const float* __restrict__ quad,
    float* __restrict__ out_d,
    float* __restrict__ out_q,
    int n)
{
    int i = blockIdx.x * blockDim.x + threadIdx.x;
    if (i >= n) return;

    int t = at[i];

    // Rotation matrix rows: R[0]=x_vec, R[1]=y_vec, R[2]=z_vec
    float R00, R01, R02, R10, R11, R12, R20, R21, R22;

    if (t == 5) {
        // 'na' type: identity frame; no gathers.
        R00 = 1.0f; R01 = 0.0f; R02 = 0.0f;
        R10 = 0.0f; R11 = 1.0f; R12 = 0.0f;
        R20 = 0.0f; R21 = 0.0f; R22 = 1.0f;
    } else {
        float cx = coords[3 * i + 0];
        float cy = coords[3 * i + 1];
        float cz = coords[3 * i + 2];

        int zi = za[i];
        float3 zv = nrm3(coords[3 * zi + 0] - cx,
                         coords[3 * zi + 1] - cy,
                         coords[3 * zi + 2] - cz);

        float3 xv;
        if (t == 4) {
            // fz_only: x = [1 - z0, z0, 0]
            xv = make_float3(1.0f - zv.x, zv.x, 0.0f);
        } else {
            int xi = xa[i];
            xv = nrm3(coords[3 * xi + 0] - cx,
                      coords[3 * xi + 1] - cy,
                      coords[3 * xi + 2] - cz);
        }

        if (t == 1) {
            // bisector
            zv = nrm3(zv.x + xv.x, zv.y + xv.y, zv.z + xv.z);
        }

        if (t == 2 || t == 3) {
            int yi = ya[i];
            float3 yn = nrm3(coords[3 * yi + 0] - cx,
                             coords[3 * yi + 1] - cy,
                             coords[3 * yi + 2] - cz);
            if (t == 2) {
                // z-bisector: x = norm(x + y_nb)
                xv = nrm3(xv.x + yn.x, xv.y + yn.y, xv.z + yn.z);
            } else {
                // trifurcated: z = norm(z + x + y_nb)
                zv = nrm3(zv.x + xv.x + yn.x, zv.y + xv.y + yn.y, zv.z + xv.z + yn.z);
            }
        }

        // Gram-Schmidt: x = norm(x - z * (z.x))
        float dzx = zv.x * xv.x + zv.y * xv.y + zv.z * xv.z;
        xv = nrm3(xv.x - zv.x * dzx, xv.y - zv.y * dzx, xv.z - zv.z * dzx);

        // y = cross(z, x)
        float3 yv = make_float3(zv.y * xv.z - zv.z * xv.y,
                                zv.z * xv.x - zv.x * xv.z,
                                zv.x * xv.y - zv.y * xv.x);

        R00 = xv.x; R01 = xv.y; R02 = xv.z;
        R10 = yv.x; R11 = yv.y; R12 = yv.z;
        R20 = zv.x; R21 = zv.y; R22 = zv.z;
    }

    // d[j] = sum_k dip[k] * R[k][j]
    float dp0 = dip[3 * i + 0];
    float dp1 = dip[3 * i + 1];
    float dp2 = dip[3 * i + 2];
    out_d[3 * i + 0] = dp0 * R00 + dp1 * R10 + dp2 * R20;
    out_d[3 * i + 1] = dp0 * R01 + dp1 * R11 + dp2 * R21;
    out_d[3 * i + 2] = dp0 * R02 + dp1 * R12 + dp2 * R22;

    // Q load
    float Q00 = quad[9 * i + 0], Q01 = quad[9 * i + 1], Q02 = quad[9 * i + 2];
    float Q10 = quad[9 * i + 3], Q11 = quad[9 * i + 4], Q12 = quad[9 * i + 5];
    float Q20 = quad[9 * i + 6], Q21 = quad[9 * i + 7], Q22 = quad[9 * i + 8];

    // M = R^T * Q : M[a][l] = sum_k R[k][a] * Q[k][l]
    float M00 = R00 * Q00 + R10 * Q10 + R20 * Q20;
    float M01 = R00 * Q01 + R10 * Q11 + R20 * Q21;
    float M02 = R00 * Q02 + R10 * Q12 + R20 * Q22;
    float M10 = R01 * Q00 + R11 * Q10 + R21 * Q20;
    float M11 = R01 * Q01 + R11 * Q11 + R21 * Q21;
    float M12 = R01 * Q02 + R11 * Q12 + R21 * Q22;
    float M20 = R02 * Q00 + R12 * Q10 + R22 * Q20;
    float M21 = R02 * Q01 + R12 * Q11 + R22 * Q21;
    float M22 = R02 * Q02 + R12 * Q12 + R22 * Q22;

    // O = M * R : O[a][b] = sum_l M[a][l] * R[l][b]
    out_q[9 * i + 0] = M00 * R00 + M01 * R10 + M02 * R20;
    out_q[9 * i + 1] = M00 * R01 + M01 * R11 + M02 * R21;
    out_q[9 * i + 2] = M00 * R02 + M01 * R12 + M02 * R22;
    out_q[9 * i + 3] = M10 * R00 + M11 * R10 + M12 * R20;
    out_q[9 * i + 4] = M10 * R01 + M11 * R11 + M12 * R21;
    out_q[9 * i + 5] = M10 * R02 + M11 * R12 + M12 * R22;
    out_q[9 * i + 6] = M20 * R00 + M21 * R10 + M22 * R20;
    out_q[9 * i + 7] = M20 * R01 + M21 * R11 + M22 * R21;
    out_q[9 * i + 8] = M20 * R02 + M21 * R12 + M22 * R22;
}

extern "C" void kernel_launch(void* const* d_in, const int* in_sizes, int n_in,
                              void* d_out, int out_size, void* d_ws, size_t ws_size,
                              hipStream_t stream) {
    const float* coords = (const float*)d_in[0];
    const int* za = (const int*)d_in[1];
    const int* xa = (const int*)d_in[2];
    const int* ya = (const int*)d_in[3];
    const int* at = (const int*)d_in[4];
    const float* dip = (const float*)d_in[5];
    const float* quad = (const float*)d_in[6];

    int n = in_sizes[1];  // z_atoms count == N
    float* out_d = (float*)d_out;
    float* out_q = out_d + (size_t)3 * n;

    int block = 256;
    int grid = (n + block - 1) / block;
    mp_rot_kernel<<<grid, block, 0, stream>>>(coords, za, xa, ya, at, dip, quad,
                                              out_d, out_q, n);
}